// Round 4
// baseline (198.163 us; speedup 1.0000x reference)
//
#include <hip/hip_runtime.h>
#include <hip/hip_bf16.h>

#define T_TOK 2048
#define D_    512
#define TWO_D 1024
#define M_    64

typedef float  f32x4  __attribute__((ext_vector_type(4)));
typedef __bf16 bf16x8 __attribute__((ext_vector_type(8)));

__device__ __forceinline__ ushort f2bf(float f) {
    union { __hip_bfloat16 h; ushort u; } cv;
    cv.h = __float2bfloat16(f);
    return cv.u;
}

// ---------------- cast x (f32) -> xs[:, 0:512] (bf16), xs is [2048][1024] ----
__global__ __launch_bounds__(256) void k_cast_x(const float* __restrict__ x,
                                                ushort* __restrict__ xs) {
    int idx = blockIdx.x * 256 + threadIdx.x;
    int e4  = idx * 4;                    // 4 consecutive elems, same row (512%4==0)
    int t   = e4 >> 9;
    int d   = e4 & 511;
    float4 v = *reinterpret_cast<const float4*>(x + e4);
    ushort4 o;
    o.x = f2bf(v.x); o.y = f2bf(v.y); o.z = f2bf(v.z); o.w = f2bf(v.w);
    *reinterpret_cast<ushort4*>(xs + (size_t)t * TWO_D + d) = o;
}

// ---------------- selector GEMM1: H = gelu(context @ sel_W1 + b1), fp32 ------
// C[2048][1024] = A[2048][512] @ B[512][1024]
__global__ __launch_bounds__(256) void k_gemm1(const float* __restrict__ A,
                                               const float* __restrict__ W1,
                                               const float* __restrict__ b1,
                                               float* __restrict__ H) {
    __shared__ float sa[64][36];   // pad 36: breaks row-bank aliasing
    __shared__ float sb[32][64];
    int tx = threadIdx.x & 15, ty = threadIdx.x >> 4;
    int col0 = blockIdx.x * 64, row0 = blockIdx.y * 64;
    float acc[4][4];
#pragma unroll
    for (int i = 0; i < 4; i++)
#pragma unroll
        for (int j = 0; j < 4; j++) acc[i][j] = 0.0f;

    for (int k0 = 0; k0 < D_; k0 += 32) {
#pragma unroll
        for (int q = 0; q < 2; q++) {
            int f = threadIdx.x * 2 + q;
            int r = f >> 3, c = (f & 7) * 4;
            *reinterpret_cast<float4*>(&sa[r][c]) =
                *reinterpret_cast<const float4*>(&A[(size_t)(row0 + r) * D_ + k0 + c]);
            int kk = f >> 4, n = (f & 15) * 4;
            *reinterpret_cast<float4*>(&sb[kk][n]) =
                *reinterpret_cast<const float4*>(&W1[(size_t)(k0 + kk) * TWO_D + col0 + n]);
        }
        __syncthreads();
#pragma unroll
        for (int kk = 0; kk < 32; kk++) {
            float a0 = sa[ty * 4 + 0][kk], a1 = sa[ty * 4 + 1][kk];
            float a2 = sa[ty * 4 + 2][kk], a3 = sa[ty * 4 + 3][kk];
            float4 b4 = *reinterpret_cast<float4*>(&sb[kk][tx * 4]);
            acc[0][0] += a0 * b4.x; acc[0][1] += a0 * b4.y; acc[0][2] += a0 * b4.z; acc[0][3] += a0 * b4.w;
            acc[1][0] += a1 * b4.x; acc[1][1] += a1 * b4.y; acc[1][2] += a1 * b4.z; acc[1][3] += a1 * b4.w;
            acc[2][0] += a2 * b4.x; acc[2][1] += a2 * b4.y; acc[2][2] += a2 * b4.z; acc[2][3] += a2 * b4.w;
            acc[3][0] += a3 * b4.x; acc[3][1] += a3 * b4.y; acc[3][2] += a3 * b4.z; acc[3][3] += a3 * b4.w;
        }
        __syncthreads();
    }
#pragma unroll
    for (int i = 0; i < 4; i++) {
        int row = row0 + ty * 4 + i;
        float4 o;
        float* oc = reinterpret_cast<float*>(&o);
#pragma unroll
        for (int j = 0; j < 4; j++) {
            int col = col0 + tx * 4 + j;
            float v = acc[i][j] + b1[col];
            oc[j] = 0.5f * v * (1.0f + erff(v * 0.70710678118654752f));  // exact gelu
        }
        *reinterpret_cast<float4*>(&H[(size_t)row * TWO_D + col0 + tx * 4]) = o;
    }
}

// ---------------- router: logits, gate, softmax, top-4, bucket ---------------
// per block: 8 tokens, 256 threads (4 waves, 2 tokens each)
__global__ __launch_bounds__(256) void k_router(const float* __restrict__ H,
                                                const float* __restrict__ x,
                                                const float* __restrict__ W2,
                                                const float* __restrict__ b2,
                                                const float* __restrict__ Wg,
                                                const float* __restrict__ bg,
                                                int* __restrict__ counts,
                                                int* __restrict__ bslot,
                                                float* __restrict__ bw) {
    __shared__ float sw[128][64];
    __shared__ float sh[8][128];
    __shared__ float slog[8][64];
    __shared__ float sglog[8][64];
    int t = threadIdx.x;
    int wave = t >> 6, lane = t & 63;
    int tok0 = blockIdx.x * 8;

    // ---- logits = H @ W2  (K=1024, 8 chunks of 128) ----
    float accL0 = 0.f, accL1 = 0.f;
    for (int c = 0; c < 8; c++) {
#pragma unroll
        for (int q = 0; q < 8; q++) {           // full [128][64] coverage
            int f = q * 256 + t;
            int d = f >> 4, m4 = (f & 15) * 4;
            *reinterpret_cast<float4*>(&sw[d][m4]) =
                *reinterpret_cast<const float4*>(&W2[(size_t)(c * 128 + d) * M_ + m4]);
        }
        {
            int r = t >> 5, d4 = (t & 31) * 4;
            *reinterpret_cast<float4*>(&sh[r][d4]) =
                *reinterpret_cast<const float4*>(&H[(size_t)(tok0 + r) * TWO_D + c * 128 + d4]);
        }
        __syncthreads();
        int tt0 = wave * 2;
        float a0 = 0.f, a1 = 0.f;
#pragma unroll 8
        for (int d = 0; d < 128; d++) {
            float wv = sw[d][lane];
            a0 += sh[tt0][d] * wv;
            a1 += sh[tt0 + 1][d] * wv;
        }
        accL0 += a0; accL1 += a1;
        __syncthreads();
    }
    slog[wave * 2 + 0][lane] = accL0 + b2[lane];
    slog[wave * 2 + 1][lane] = accL1 + b2[lane];

    // ---- gate logits = x @ Wg^T  (K=512, 4 chunks) ----
    float accG0 = 0.f, accG1 = 0.f;
    for (int c = 0; c < 4; c++) {
        {
            int m = t >> 2, qq = t & 3;
#pragma unroll
            for (int u = 0; u < 8; u++) {
                int d = qq * 32 + u * 4;
                float4 v = *reinterpret_cast<const float4*>(&Wg[(size_t)m * D_ + c * 128 + d]);
                sw[d + 0][m] = v.x; sw[d + 1][m] = v.y; sw[d + 2][m] = v.z; sw[d + 3][m] = v.w;
            }
        }
        {
            int r = t >> 5, d4 = (t & 31) * 4;
            *reinterpret_cast<float4*>(&sh[r][d4]) =
                *reinterpret_cast<const float4*>(&x[(size_t)(tok0 + r) * D_ + c * 128 + d4]);
        }
        __syncthreads();
        int tt0 = wave * 2;
        float a0 = 0.f, a1 = 0.f;
#pragma unroll 8
        for (int d = 0; d < 128; d++) {
            float wv = sw[d][lane];
            a0 += sh[tt0][d] * wv;
            a1 += sh[tt0 + 1][d] * wv;
        }
        accG0 += a0; accG1 += a1;
        __syncthreads();
    }
    sglog[wave * 2 + 0][lane] = accG0 + bg[lane];
    sglog[wave * 2 + 1][lane] = accG1 + bg[lane];
    __syncthreads();

    // ---- per-token softmax, top-4 (lowest-index tiebreak), bucket write ----
    for (int t2 = 0; t2 < 2; t2++) {
        int tt = wave * 2 + t2;
        int token = tok0 + tt;
        float l = slog[tt][lane];
        float mx = l;
#pragma unroll
        for (int off = 1; off < 64; off <<= 1) mx = fmaxf(mx, __shfl_xor(mx, off));
        float ev = expf(l - mx);
        float s = ev;
#pragma unroll
        for (int off = 1; off < 64; off <<= 1) s += __shfl_xor(s, off);
        float p = ev / s;

        float pm = p;
        int bi0, bi1, bi2, bi3; float bv0, bv1, bv2, bv3;
#pragma unroll
        for (int k = 0; k < 4; k++) {
            float bv = pm; int bi = lane;
#pragma unroll
            for (int off = 1; off < 64; off <<= 1) {
                float ov = __shfl_xor(bv, off);
                int   oi = __shfl_xor(bi, off);
                if (ov > bv || (ov == bv && oi < bi)) { bv = ov; bi = oi; }
            }
            if (k == 0) { bi0 = bi; bv0 = bv; }
            else if (k == 1) { bi1 = bi; bv1 = bv; }
            else if (k == 2) { bi2 = bi; bv2 = bv; }
            else { bi3 = bi; bv3 = bv; }
            if (lane == bi) pm = -1.0f;
        }
        float sum4 = bv0 + bv1 + bv2 + bv3;
        if (lane < 4) {
            int   e  = (lane == 0) ? bi0 : (lane == 1) ? bi1 : (lane == 2) ? bi2 : bi3;
            float pv = (lane == 0) ? bv0 : (lane == 1) ? bv1 : (lane == 2) ? bv2 : bv3;
            float g  = 1.0f / (1.0f + expf(-sglog[tt][e]));
            float w  = (pv / sum4) * g;
            int pos = atomicAdd(&counts[e], 1);
            bslot[e * T_TOK + pos] = token * 4 + lane;
            bw[e * T_TOK + pos]   = w;
        }
    }
}

// ---------------- grouped expert GEMM (bf16 MFMA) ---------------------------
// per block: expert e, 64 bucket rows x 64 out cols, K=512
__global__ __launch_bounds__(256) void k_expert(const ushort* __restrict__ xs,
                                                const float* __restrict__ Wt,
                                                const float* __restrict__ bt,
                                                const float* __restrict__ ch,
                                                const int* __restrict__ counts,
                                                const int* __restrict__ bslot,
                                                const float* __restrict__ bw,
                                                float* __restrict__ scratch) {
    int e   = blockIdx.z;
    int cnt = counts[e];
    int y0  = blockIdx.y * 64;
    if (y0 >= cnt) return;
    int n0 = blockIdx.x * 64;

    __shared__ ushort sa[64][40];    // [row][k], pad 40 -> 2-way-free banks
    __shared__ ushort sbT[64][40];   // [n][k]
    __shared__ int    s_slot[64];
    __shared__ float  s_w[64];

    int t = threadIdx.x;
    if (t < 64) {
        int i = y0 + t;
        if (i < cnt) { s_slot[t] = bslot[e * T_TOK + i]; s_w[t] = bw[e * T_TOK + i]; }
        else         { s_slot[t] = -1;                   s_w[t] = 0.0f; }
    }
    __syncthreads();

    int lane = t & 63, wave = t >> 6;
    int wm = wave >> 1, wn = wave & 1;
    int lr = lane & 15, kq = lane >> 4;

    f32x4 acc[2][2];
#pragma unroll
    for (int i = 0; i < 2; i++)
#pragma unroll
        for (int j = 0; j < 2; j++)
#pragma unroll
            for (int r = 0; r < 4; r++) acc[i][j][r] = 0.0f;

    for (int k0 = 0; k0 < D_; k0 += 32) {
        {   // stage gathered A rows (bf16 already)
            int r = t >> 2, q = t & 3;
            int slot = s_slot[r];
            int tok = (slot >= 0) ? (slot >> 2) : 0;
            *reinterpret_cast<int4*>(&sa[r][q * 8]) =
                *reinterpret_cast<const int4*>(xs + (size_t)tok * TWO_D + k0 + q * 8);
        }
        {   // stage B transposed + fp32->bf16
#pragma unroll
            for (int q = 0; q < 2; q++) {
                int f = t * 2 + q;
                int k = f >> 4, n4 = (f & 15) * 4;
                float4 v = *reinterpret_cast<const float4*>(
                    &Wt[((size_t)e * D_ + (k0 + k)) * D_ + n0 + n4]);
                sbT[n4 + 0][k] = f2bf(v.x); sbT[n4 + 1][k] = f2bf(v.y);
                sbT[n4 + 2][k] = f2bf(v.z); sbT[n4 + 3][k] = f2bf(v.w);
            }
        }
        __syncthreads();
        bf16x8 af[2], bfr[2];
#pragma unroll
        for (int i = 0; i < 2; i++)
            af[i] = *reinterpret_cast<const bf16x8*>(&sa[wm * 32 + i * 16 + lr][kq * 8]);
#pragma unroll
        for (int j = 0; j < 2; j++)
            bfr[j] = *reinterpret_cast<const bf16x8*>(&sbT[wn * 32 + j * 16 + lr][kq * 8]);
#pragma unroll
        for (int i = 0; i < 2; i++)
#pragma unroll
            for (int j = 0; j < 2; j++)
                acc[i][j] = __builtin_amdgcn_mfma_f32_16x16x32_bf16(af[i], bfr[j], acc[i][j], 0, 0, 0);
        __syncthreads();
    }

#pragma unroll
    for (int i = 0; i < 2; i++)
#pragma unroll
        for (int j = 0; j < 2; j++) {
            int col = n0 + wn * 32 + j * 16 + lr;
            float bias = bt[(size_t)e * D_ + col] + ch[(size_t)e * D_ + col];
#pragma unroll
            for (int r = 0; r < 4; r++) {
                int rl = wm * 32 + i * 16 + kq * 4 + r;
                int slot = s_slot[rl];
                if (slot >= 0)
                    scratch[(size_t)slot * D_ + col] = (acc[i][j][r] + bias) * s_w[rl];
            }
        }
}

// ---------------- combine 4 slots -> selected (bf16) into xs[:, 512:] -------
__global__ __launch_bounds__(256) void k_combine(const float* __restrict__ scratch,
                                                 ushort* __restrict__ xs) {
    int tid = blockIdx.x * 256 + threadIdx.x;
    int token = tid >> 7;
    int d4 = (tid & 127) * 4;
    float4 a = *reinterpret_cast<const float4*>(scratch + ((size_t)token * 4 + 0) * D_ + d4);
    float4 b = *reinterpret_cast<const float4*>(scratch + ((size_t)token * 4 + 1) * D_ + d4);
    float4 c = *reinterpret_cast<const float4*>(scratch + ((size_t)token * 4 + 2) * D_ + d4);
    float4 d = *reinterpret_cast<const float4*>(scratch + ((size_t)token * 4 + 3) * D_ + d4);
    ushort4 o;
    o.x = f2bf(a.x + b.x + c.x + d.x);
    o.y = f2bf(a.y + b.y + c.y + d.y);
    o.z = f2bf(a.z + b.z + c.z + d.z);
    o.w = f2bf(a.w + b.w + c.w + d.w);
    *reinterpret_cast<ushort4*>(xs + (size_t)token * TWO_D + D_ + d4) = o;
}

// ---------------- integrate: out = [x, selected] @ int_W + int_b (bf16 MFMA)-
__global__ __launch_bounds__(256) void k_integrate(const ushort* __restrict__ xs,
                                                   const float* __restrict__ Wi,
                                                   const float* __restrict__ bi,
                                                   float* __restrict__ out) {
    int n0 = blockIdx.x * 64, r0 = blockIdx.y * 64;
    __shared__ ushort sa[64][40];
    __shared__ ushort sbT[64][40];
    int t = threadIdx.x, lane = t & 63, wave = t >> 6;
    int wm = wave >> 1, wn = wave & 1;
    int lr = lane & 15, kq = lane >> 4;

    f32x4 acc[2][2];
#pragma unroll
    for (int i = 0; i < 2; i++)
#pragma unroll
        for (int j = 0; j < 2; j++)
#pragma unroll
            for (int r = 0; r < 4; r++) acc[i][j][r] = 0.0f;

    for (int k0 = 0; k0 < TWO_D; k0 += 32) {
        {
            int r = t >> 2, q = t & 3;
            *reinterpret_cast<int4*>(&sa[r][q * 8]) =
                *reinterpret_cast<const int4*>(xs + (size_t)(r0 + r) * TWO_D + k0 + q * 8);
        }
        {
#pragma unroll
            for (int q = 0; q < 2; q++) {
                int f = t * 2 + q;
                int k = f >> 4, n4 = (f & 15) * 4;
                float4 v = *reinterpret_cast<const float4*>(&Wi[(size_t)(k0 + k) * D_ + n0 + n4]);
                sbT[n4 + 0][k] = f2bf(v.x); sbT[n4 + 1][k] = f2bf(v.y);
                sbT[n4 + 2][k] = f2bf(v.z); sbT[n4 + 3][k] = f2bf(v.w);
            }
        }
        __syncthreads();
        bf16x8 af[2], bfr[2];
#pragma unroll
        for (int i = 0; i < 2; i++)
            af[i] = *reinterpret_cast<const bf16x8*>(&sa[wm * 32 + i * 16 + lr][kq * 8]);
#pragma unroll
        for (int j = 0; j < 2; j++)
            bfr[j] = *reinterpret_cast<const bf16x8*>(&sbT[wn * 32 + j * 16 + lr][kq * 8]);
#pragma unroll
        for (int i = 0; i < 2; i++)
#pragma unroll
            for (int j = 0; j < 2; j++)
                acc[i][j] = __builtin_amdgcn_mfma_f32_16x16x32_bf16(af[i], bfr[j], acc[i][j], 0, 0, 0);
        __syncthreads();
    }

#pragma unroll
    for (int i = 0; i < 2; i++)
#pragma unroll
        for (int j = 0; j < 2; j++) {
            int col = n0 + wn * 32 + j * 16 + lr;
            float bb = bi[col];
#pragma unroll
            for (int r = 0; r < 4; r++) {
                int row = r0 + wm * 32 + i * 16 + kq * 4 + r;
                out[(size_t)row * D_ + col] = acc[i][j][r] + bb;
            }
        }
}

extern "C" void kernel_launch(void* const* d_in, const int* in_sizes, int n_in,
                              void* d_out, int out_size, void* d_ws, size_t ws_size,
                              hipStream_t stream) {
    const float* x   = (const float*)d_in[0];
    const float* ctx = (const float*)d_in[1];
    const float* Wt  = (const float*)d_in[2];
    const float* bt  = (const float*)d_in[3];
    const float* ch  = (const float*)d_in[4];
    const float* Wg  = (const float*)d_in[5];
    const float* bg  = (const float*)d_in[6];
    const float* W1  = (const float*)d_in[7];
    const float* b1  = (const float*)d_in[8];
    const float* W2  = (const float*)d_in[9];
    const float* b2  = (const float*)d_in[10];
    const float* Wi  = (const float*)d_in[11];
    const float* bi  = (const float*)d_in[12];
    float* out = (float*)d_out;

    char* ws = (char*)d_ws;
    float*  H       = (float*)(ws + 0);                 //  8 MB  [2048][1024] f32
    ushort* xs      = (ushort*)(ws + 8388608);          //  4 MB  [2048][1024] bf16
    int*    counts  = (int*)(ws + 12582912);            //  1 KB
    int*    bslot   = (int*)(ws + 12583936);            // 512 KB [64][2048]
    float*  bw      = (float*)(ws + 13108224);          // 512 KB
    float*  scratch = (float*)(ws + 13632512);          // 16 MB  [8192][512] f32

    hipMemsetAsync(counts, 0, 256, stream);
    k_cast_x  <<<1024, 256, 0, stream>>>(x, xs);
    k_gemm1   <<<dim3(16, 32), 256, 0, stream>>>(ctx, W1, b1, H);
    k_router  <<<256, 256, 0, stream>>>(H, x, W2, b2, Wg, bg, counts, bslot, bw);
    k_expert  <<<dim3(8, 32, 64), 256, 0, stream>>>(xs, Wt, bt, ch, counts, bslot, bw, scratch);
    k_combine <<<1024, 256, 0, stream>>>(scratch, xs);
    k_integrate<<<dim3(8, 32), 256, 0, stream>>>(xs, Wi, bi, out);
}

// Round 5
// 184.301 us; speedup vs baseline: 1.0752x; 1.0752x over previous
//
#include <hip/hip_runtime.h>
#include <hip/hip_bf16.h>

#define T_TOK 2048
#define D_    512
#define TWO_D 1024
#define M_    64

typedef float  f32x4  __attribute__((ext_vector_type(4)));
typedef __bf16 bf16x8 __attribute__((ext_vector_type(8)));

__device__ __forceinline__ ushort f2bf(float f) {
    union { __hip_bfloat16 h; ushort u; } cv;
    cv.h = __float2bfloat16(f);
    return cv.u;
}

// ---------------- cast x (f32) -> xs[:, 0:512] (bf16), xs is [2048][1024] ----
__global__ __launch_bounds__(256) void k_cast_x(const float* __restrict__ x,
                                                ushort* __restrict__ xs) {
    int idx = blockIdx.x * 256 + threadIdx.x;
    int e4  = idx * 4;
    int t   = e4 >> 9;
    int d   = e4 & 511;
    float4 v = *reinterpret_cast<const float4*>(x + e4);
    ushort4 o;
    o.x = f2bf(v.x); o.y = f2bf(v.y); o.z = f2bf(v.z); o.w = f2bf(v.w);
    *reinterpret_cast<ushort4*>(xs + (size_t)t * TWO_D + d) = o;
}

// ---------------- selector GEMM1: H = gelu(context @ sel_W1 + b1), fp32 ------
// C[2048][1024] = A[2048][512] @ B[512][1024].  A staged TRANSPOSED so the
// inner iter is 2x ds_read_b128 + 16 FMA.
__global__ __launch_bounds__(256) void k_gemm1(const float* __restrict__ A,
                                               const float* __restrict__ W1,
                                               const float* __restrict__ b1,
                                               float* __restrict__ H) {
    __shared__ float sa_t[32][72];   // [k][row], pad 72
    __shared__ float sb[32][64];     // [k][col]
    int tx = threadIdx.x & 15, ty = threadIdx.x >> 4;
    int col0 = blockIdx.x * 64, row0 = blockIdx.y * 64;
    float acc[4][4];
#pragma unroll
    for (int i = 0; i < 4; i++)
#pragma unroll
        for (int j = 0; j < 4; j++) acc[i][j] = 0.0f;

    for (int k0 = 0; k0 < D_; k0 += 32) {
#pragma unroll
        for (int q = 0; q < 2; q++) {
            int f = threadIdx.x * 2 + q;
            int r = f >> 3, c4 = (f & 7) * 4;
            float4 v = *reinterpret_cast<const float4*>(&A[(size_t)(row0 + r) * D_ + k0 + c4]);
            sa_t[c4 + 0][r] = v.x; sa_t[c4 + 1][r] = v.y;
            sa_t[c4 + 2][r] = v.z; sa_t[c4 + 3][r] = v.w;
            int kk = f >> 4, n = (f & 15) * 4;
            *reinterpret_cast<float4*>(&sb[kk][n]) =
                *reinterpret_cast<const float4*>(&W1[(size_t)(k0 + kk) * TWO_D + col0 + n]);
        }
        __syncthreads();
#pragma unroll
        for (int kk = 0; kk < 32; kk++) {
            float4 a4 = *reinterpret_cast<float4*>(&sa_t[kk][ty * 4]);
            float4 b4 = *reinterpret_cast<float4*>(&sb[kk][tx * 4]);
            const float* ap = reinterpret_cast<const float*>(&a4);
            const float* bp = reinterpret_cast<const float*>(&b4);
#pragma unroll
            for (int i = 0; i < 4; i++)
#pragma unroll
                for (int j = 0; j < 4; j++) acc[i][j] += ap[i] * bp[j];
        }
        __syncthreads();
    }
#pragma unroll
    for (int i = 0; i < 4; i++) {
        int row = row0 + ty * 4 + i;
        float4 o;
        float* oc = reinterpret_cast<float*>(&o);
#pragma unroll
        for (int j = 0; j < 4; j++) {
            int col = col0 + tx * 4 + j;
            float v = acc[i][j] + b1[col];
            oc[j] = 0.5f * v * (1.0f + erff(v * 0.70710678118654752f));
        }
        *reinterpret_cast<float4*>(&H[(size_t)row * TWO_D + col0 + tx * 4]) = o;
    }
}

// ---------------- logits partials: fp32 GEMM, K split across blocks ----------
// grid (12 chunks, 32 token-blocks). chunks 0-7: H@W2 (K=1024), 8-11: x@Wg^T.
// partial[chunk][tok][m]
__global__ __launch_bounds__(256) void k_logits(const float* __restrict__ H,
                                                const float* __restrict__ x,
                                                const float* __restrict__ W2,
                                                const float* __restrict__ Wg,
                                                float* __restrict__ partial) {
    __shared__ float sa_t[32][72];
    __shared__ float sb[32][64];
    int tx = threadIdx.x & 15, ty = threadIdx.x >> 4;
    int cx = blockIdx.x;
    int row0 = blockIdx.y * 64;

    const float* Asrc; int lda, koff;
    if (cx < 8) { Asrc = H; lda = TWO_D; koff = cx * 128; }
    else        { Asrc = x; lda = D_;    koff = (cx - 8) * 128; }

    float acc[4][4];
#pragma unroll
    for (int i = 0; i < 4; i++)
#pragma unroll
        for (int j = 0; j < 4; j++) acc[i][j] = 0.0f;

    for (int k0 = 0; k0 < 128; k0 += 32) {
#pragma unroll
        for (int q = 0; q < 2; q++) {
            int f = threadIdx.x * 2 + q;
            int r = f >> 3, c4 = (f & 7) * 4;
            float4 v = *reinterpret_cast<const float4*>(&Asrc[(size_t)(row0 + r) * lda + koff + k0 + c4]);
            sa_t[c4 + 0][r] = v.x; sa_t[c4 + 1][r] = v.y;
            sa_t[c4 + 2][r] = v.z; sa_t[c4 + 3][r] = v.w;
            if (cx < 8) {
                int kk = f >> 4, n4 = (f & 15) * 4;
                *reinterpret_cast<float4*>(&sb[kk][n4]) =
                    *reinterpret_cast<const float4*>(&W2[(size_t)(koff + k0 + kk) * M_ + n4]);
            } else {
                int m = f >> 3, kq = f & 7;
                float4 v2 = *reinterpret_cast<const float4*>(&Wg[(size_t)m * D_ + koff + k0 + kq * 4]);
                sb[kq * 4 + 0][m] = v2.x; sb[kq * 4 + 1][m] = v2.y;
                sb[kq * 4 + 2][m] = v2.z; sb[kq * 4 + 3][m] = v2.w;
            }
        }
        __syncthreads();
#pragma unroll
        for (int kk = 0; kk < 32; kk++) {
            float4 a4 = *reinterpret_cast<float4*>(&sa_t[kk][ty * 4]);
            float4 b4 = *reinterpret_cast<float4*>(&sb[kk][tx * 4]);
            const float* ap = reinterpret_cast<const float*>(&a4);
            const float* bp = reinterpret_cast<const float*>(&b4);
#pragma unroll
            for (int i = 0; i < 4; i++)
#pragma unroll
                for (int j = 0; j < 4; j++) acc[i][j] += ap[i] * bp[j];
        }
        __syncthreads();
    }
#pragma unroll
    for (int i = 0; i < 4; i++) {
        int row = row0 + ty * 4 + i;
        float4 o;
        float* oc = reinterpret_cast<float*>(&o);
#pragma unroll
        for (int j = 0; j < 4; j++) oc[j] = acc[i][j];
        *reinterpret_cast<float4*>(&partial[((size_t)cx * T_TOK + row) * M_ + tx * 4]) = o;
    }
}

// ---------------- top-k: reduce partials, softmax, top-4, bucket -------------
// per block: 8 tokens, 4 waves, wave handles 2 tokens; lane = expert m
__global__ __launch_bounds__(256) void k_topk(const float* __restrict__ partial,
                                              const float* __restrict__ b2,
                                              const float* __restrict__ bg,
                                              int* __restrict__ counts,
                                              int* __restrict__ bslot,
                                              float* __restrict__ bw) {
    __shared__ float sglog[8][64];
    int t = threadIdx.x;
    int wave = t >> 6, lane = t & 63;
    int tok0 = blockIdx.x * 8;

    float l0, l1;
#pragma unroll
    for (int t2 = 0; t2 < 2; t2++) {
        int tok = tok0 + wave * 2 + t2;
        float acc = b2[lane];
#pragma unroll
        for (int c = 0; c < 8; c++)
            acc += partial[((size_t)c * T_TOK + tok) * M_ + lane];
        if (t2 == 0) l0 = acc; else l1 = acc;
        float ga = bg[lane];
#pragma unroll
        for (int c = 8; c < 12; c++)
            ga += partial[((size_t)c * T_TOK + tok) * M_ + lane];
        sglog[wave * 2 + t2][lane] = ga;
    }
    __syncthreads();

    for (int t2 = 0; t2 < 2; t2++) {
        int tt = wave * 2 + t2;
        int token = tok0 + tt;
        float l = (t2 == 0) ? l0 : l1;
        float mx = l;
#pragma unroll
        for (int off = 1; off < 64; off <<= 1) mx = fmaxf(mx, __shfl_xor(mx, off));
        float ev = expf(l - mx);
        float s = ev;
#pragma unroll
        for (int off = 1; off < 64; off <<= 1) s += __shfl_xor(s, off);
        float p = ev / s;

        float pm = p;
        int bi0, bi1, bi2, bi3; float bv0, bv1, bv2, bv3;
#pragma unroll
        for (int k = 0; k < 4; k++) {
            float bv = pm; int bi = lane;
#pragma unroll
            for (int off = 1; off < 64; off <<= 1) {
                float ov = __shfl_xor(bv, off);
                int   oi = __shfl_xor(bi, off);
                if (ov > bv || (ov == bv && oi < bi)) { bv = ov; bi = oi; }
            }
            if (k == 0) { bi0 = bi; bv0 = bv; }
            else if (k == 1) { bi1 = bi; bv1 = bv; }
            else if (k == 2) { bi2 = bi; bv2 = bv; }
            else { bi3 = bi; bv3 = bv; }
            if (lane == bi) pm = -1.0f;
        }
        float sum4 = bv0 + bv1 + bv2 + bv3;
        if (lane < 4) {
            int   e  = (lane == 0) ? bi0 : (lane == 1) ? bi1 : (lane == 2) ? bi2 : bi3;
            float pv = (lane == 0) ? bv0 : (lane == 1) ? bv1 : (lane == 2) ? bv2 : bv3;
            float g  = 1.0f / (1.0f + expf(-sglog[tt][e]));
            float w  = (pv / sum4) * g;
            int pos = atomicAdd(&counts[e], 1);
            bslot[e * T_TOK + pos] = token * 4 + lane;
            bw[e * T_TOK + pos]   = w;
        }
    }
}

// ---------------- grouped expert GEMM (bf16 MFMA), 128-row y-tiles ----------
// per block: expert e, 128 bucket rows x 64 out cols, K=512
__global__ __launch_bounds__(256) void k_expert(const ushort* __restrict__ xs,
                                                const float* __restrict__ Wt,
                                                const float* __restrict__ bt,
                                                const float* __restrict__ ch,
                                                const int* __restrict__ counts,
                                                const int* __restrict__ bslot,
                                                const float* __restrict__ bw,
                                                float* __restrict__ scratch) {
    int e   = blockIdx.z;
    int cnt = counts[e];
    int y0  = blockIdx.y * 128;
    if (y0 >= cnt) return;
    int n0 = blockIdx.x * 64;

    __shared__ ushort sa[128][40];
    __shared__ ushort sbT[64][40];
    __shared__ int    s_slot[128];
    __shared__ float  s_w[128];

    int t = threadIdx.x;
    if (t < 128) {
        int i = y0 + t;
        if (i < cnt) { s_slot[t] = bslot[e * T_TOK + i]; s_w[t] = bw[e * T_TOK + i]; }
        else         { s_slot[t] = -1;                   s_w[t] = 0.0f; }
    }
    __syncthreads();

    int lane = t & 63, wave = t >> 6;
    int lr = lane & 15, kq = lane >> 4;

    f32x4 acc[2][4];
#pragma unroll
    for (int i = 0; i < 2; i++)
#pragma unroll
        for (int j = 0; j < 4; j++)
#pragma unroll
            for (int r = 0; r < 4; r++) acc[i][j][r] = 0.0f;

    for (int k0 = 0; k0 < D_; k0 += 32) {
        {   // stage gathered A rows: 128 rows x 32 k bf16 = 512 int4
#pragma unroll
            for (int q = 0; q < 2; q++) {
                int f = t * 2 + q;
                int r = f >> 2, qq = f & 3;
                int slot = s_slot[r];
                int tok = (slot >= 0) ? (slot >> 2) : 0;
                *reinterpret_cast<int4*>(&sa[r][qq * 8]) =
                    *reinterpret_cast<const int4*>(xs + (size_t)tok * TWO_D + k0 + qq * 8);
            }
        }
        {   // stage B transposed + fp32->bf16
#pragma unroll
            for (int q = 0; q < 2; q++) {
                int f = t * 2 + q;
                int k = f >> 4, n4 = (f & 15) * 4;
                float4 v = *reinterpret_cast<const float4*>(
                    &Wt[((size_t)e * D_ + (k0 + k)) * D_ + n0 + n4]);
                sbT[n4 + 0][k] = f2bf(v.x); sbT[n4 + 1][k] = f2bf(v.y);
                sbT[n4 + 2][k] = f2bf(v.z); sbT[n4 + 3][k] = f2bf(v.w);
            }
        }
        __syncthreads();
        bf16x8 af[2], bfr[4];
#pragma unroll
        for (int i = 0; i < 2; i++)
            af[i] = *reinterpret_cast<const bf16x8*>(&sa[wave * 32 + i * 16 + lr][kq * 8]);
#pragma unroll
        for (int j = 0; j < 4; j++)
            bfr[j] = *reinterpret_cast<const bf16x8*>(&sbT[j * 16 + lr][kq * 8]);
#pragma unroll
        for (int i = 0; i < 2; i++)
#pragma unroll
            for (int j = 0; j < 4; j++)
                acc[i][j] = __builtin_amdgcn_mfma_f32_16x16x32_bf16(af[i], bfr[j], acc[i][j], 0, 0, 0);
        __syncthreads();
    }

#pragma unroll
    for (int i = 0; i < 2; i++)
#pragma unroll
        for (int j = 0; j < 4; j++) {
            int col = n0 + j * 16 + lr;
            float bias = bt[(size_t)e * D_ + col] + ch[(size_t)e * D_ + col];
#pragma unroll
            for (int r = 0; r < 4; r++) {
                int rl = wave * 32 + i * 16 + kq * 4 + r;
                int slot = s_slot[rl];
                if (slot >= 0)
                    scratch[(size_t)slot * D_ + col] = (acc[i][j][r] + bias) * s_w[rl];
            }
        }
}

// ---------------- combine 4 slots -> selected (bf16) into xs[:, 512:] -------
__global__ __launch_bounds__(256) void k_combine(const float* __restrict__ scratch,
                                                 ushort* __restrict__ xs) {
    int tid = blockIdx.x * 256 + threadIdx.x;
    int token = tid >> 7;
    int d4 = (tid & 127) * 4;
    float4 a = *reinterpret_cast<const float4*>(scratch + ((size_t)token * 4 + 0) * D_ + d4);
    float4 b = *reinterpret_cast<const float4*>(scratch + ((size_t)token * 4 + 1) * D_ + d4);
    float4 c = *reinterpret_cast<const float4*>(scratch + ((size_t)token * 4 + 2) * D_ + d4);
    float4 d = *reinterpret_cast<const float4*>(scratch + ((size_t)token * 4 + 3) * D_ + d4);
    ushort4 o;
    o.x = f2bf(a.x + b.x + c.x + d.x);
    o.y = f2bf(a.y + b.y + c.y + d.y);
    o.z = f2bf(a.z + b.z + c.z + d.z);
    o.w = f2bf(a.w + b.w + c.w + d.w);
    *reinterpret_cast<ushort4*>(xs + (size_t)token * TWO_D + D_ + d4) = o;
}

// ---------------- integrate: out = [x, selected] @ int_W + int_b (bf16 MFMA)-
__global__ __launch_bounds__(256) void k_integrate(const ushort* __restrict__ xs,
                                                   const float* __restrict__ Wi,
                                                   const float* __restrict__ bi,
                                                   float* __restrict__ out) {
    int n0 = blockIdx.x * 64, r0 = blockIdx.y * 64;
    __shared__ ushort sa[64][40];
    __shared__ ushort sbT[64][40];
    int t = threadIdx.x, lane = t & 63, wave = t >> 6;
    int wm = wave >> 1, wn = wave & 1;
    int lr = lane & 15, kq = lane >> 4;

    f32x4 acc[2][2];
#pragma unroll
    for (int i = 0; i < 2; i++)
#pragma unroll
        for (int j = 0; j < 2; j++)
#pragma unroll
            for (int r = 0; r < 4; r++) acc[i][j][r] = 0.0f;

    for (int k0 = 0; k0 < TWO_D; k0 += 32) {
        {
            int r = t >> 2, q = t & 3;
            *reinterpret_cast<int4*>(&sa[r][q * 8]) =
                *reinterpret_cast<const int4*>(xs + (size_t)(r0 + r) * TWO_D + k0 + q * 8);
        }
        {
#pragma unroll
            for (int q = 0; q < 2; q++) {
                int f = t * 2 + q;
                int k = f >> 4, n4 = (f & 15) * 4;
                float4 v = *reinterpret_cast<const float4*>(&Wi[(size_t)(k0 + k) * D_ + n0 + n4]);
                sbT[n4 + 0][k] = f2bf(v.x); sbT[n4 + 1][k] = f2bf(v.y);
                sbT[n4 + 2][k] = f2bf(v.z); sbT[n4 + 3][k] = f2bf(v.w);
            }
        }
        __syncthreads();
        bf16x8 af[2], bfr[2];
#pragma unroll
        for (int i = 0; i < 2; i++)
            af[i] = *reinterpret_cast<const bf16x8*>(&sa[wm * 32 + i * 16 + lr][kq * 8]);
#pragma unroll
        for (int j = 0; j < 2; j++)
            bfr[j] = *reinterpret_cast<const bf16x8*>(&sbT[wn * 32 + j * 16 + lr][kq * 8]);
#pragma unroll
        for (int i = 0; i < 2; i++)
#pragma unroll
            for (int j = 0; j < 2; j++)
                acc[i][j] = __builtin_amdgcn_mfma_f32_16x16x32_bf16(af[i], bfr[j], acc[i][j], 0, 0, 0);
        __syncthreads();
    }

#pragma unroll
    for (int i = 0; i < 2; i++)
#pragma unroll
        for (int j = 0; j < 2; j++) {
            int col = n0 + wn * 32 + j * 16 + lr;
            float bb = bi[col];
#pragma unroll
            for (int r = 0; r < 4; r++) {
                int row = r0 + wm * 32 + i * 16 + kq * 4 + r;
                out[(size_t)row * D_ + col] = acc[i][j][r] + bb;
            }
        }
}

extern "C" void kernel_launch(void* const* d_in, const int* in_sizes, int n_in,
                              void* d_out, int out_size, void* d_ws, size_t ws_size,
                              hipStream_t stream) {
    const float* x   = (const float*)d_in[0];
    const float* ctx = (const float*)d_in[1];
    const float* Wt  = (const float*)d_in[2];
    const float* bt  = (const float*)d_in[3];
    const float* ch  = (const float*)d_in[4];
    const float* Wg  = (const float*)d_in[5];
    const float* bg  = (const float*)d_in[6];
    const float* W1  = (const float*)d_in[7];
    const float* b1  = (const float*)d_in[8];
    const float* W2  = (const float*)d_in[9];
    const float* b2  = (const float*)d_in[10];
    const float* Wi  = (const float*)d_in[11];
    const float* bi  = (const float*)d_in[12];
    float* out = (float*)d_out;

    char* ws = (char*)d_ws;
    float*  H       = (float*)(ws + 0);                 //  8 MB  [2048][1024] f32
    ushort* xs      = (ushort*)(ws + 8388608);          //  4 MB  [2048][1024] bf16
    int*    counts  = (int*)(ws + 12582912);            //  1 KB
    int*    bslot   = (int*)(ws + 12583936);            // 512 KB [64][2048]
    float*  bw      = (float*)(ws + 13108224);          // 512 KB
    float*  scratch = (float*)(ws + 13632512);          // 16 MB  [8192][512] f32
    float*  partial = scratch;                          //  6 MB alias (dead before expert)

    hipMemsetAsync(counts, 0, 256, stream);
    k_cast_x  <<<1024, 256, 0, stream>>>(x, xs);
    k_gemm1   <<<dim3(16, 32), 256, 0, stream>>>(ctx, W1, b1, H);
    k_logits  <<<dim3(12, 32), 256, 0, stream>>>(H, x, W2, Wg, partial);
    k_topk    <<<256, 256, 0, stream>>>(partial, b2, bg, counts, bslot, bw);
    k_expert  <<<dim3(8, 16, 64), 256, 0, stream>>>(xs, Wt, bt, ch, counts, bslot, bw, scratch);
    k_combine <<<1024, 256, 0, stream>>>(scratch, xs);
    k_integrate<<<dim3(8, 32), 256, 0, stream>>>(xs, Wi, bi, out);
}

// Round 6
// 178.855 us; speedup vs baseline: 1.1080x; 1.0305x over previous
//
#include <hip/hip_runtime.h>
#include <hip/hip_bf16.h>

#define T_TOK 2048
#define D_    512
#define TWO_D 1024
#define M_    64

typedef float  f32x4  __attribute__((ext_vector_type(4)));
typedef __bf16 bf16x8 __attribute__((ext_vector_type(8)));

__device__ __forceinline__ ushort f2bf(float f) {
    union { __hip_bfloat16 h; ushort u; } cv;
    cv.h = __float2bfloat16(f);
    return cv.u;
}

// ---------------- cast x (f32) -> xs[:, 0:512] (bf16), xs is [2048][1024] ----
__global__ __launch_bounds__(256) void k_cast_x(const float* __restrict__ x,
                                                ushort* __restrict__ xs) {
    int idx = blockIdx.x * 256 + threadIdx.x;
    int e4  = idx * 4;
    int t   = e4 >> 9;
    int d   = e4 & 511;
    float4 v = *reinterpret_cast<const float4*>(x + e4);
    ushort4 o;
    o.x = f2bf(v.x); o.y = f2bf(v.y); o.z = f2bf(v.z); o.w = f2bf(v.w);
    *reinterpret_cast<ushort4*>(xs + (size_t)t * TWO_D + d) = o;
}

// ---------------- selector GEMM1: H = gelu(context @ sel_W1 + b1), fp32 ------
// Round-3 proven version: A staged row-major, scalar broadcast A-reads.
__global__ __launch_bounds__(256) void k_gemm1(const float* __restrict__ A,
                                               const float* __restrict__ W1,
                                               const float* __restrict__ b1,
                                               float* __restrict__ H) {
    __shared__ float sa[64][36];
    __shared__ float sb[32][64];
    int tx = threadIdx.x & 15, ty = threadIdx.x >> 4;
    int col0 = blockIdx.x * 64, row0 = blockIdx.y * 64;
    float acc[4][4];
#pragma unroll
    for (int i = 0; i < 4; i++)
#pragma unroll
        for (int j = 0; j < 4; j++) acc[i][j] = 0.0f;

    for (int k0 = 0; k0 < D_; k0 += 32) {
#pragma unroll
        for (int q = 0; q < 2; q++) {
            int f = threadIdx.x * 2 + q;
            int r = f >> 3, c = (f & 7) * 4;
            *reinterpret_cast<float4*>(&sa[r][c]) =
                *reinterpret_cast<const float4*>(&A[(size_t)(row0 + r) * D_ + k0 + c]);
            int kk = f >> 4, n = (f & 15) * 4;
            *reinterpret_cast<float4*>(&sb[kk][n]) =
                *reinterpret_cast<const float4*>(&W1[(size_t)(k0 + kk) * TWO_D + col0 + n]);
        }
        __syncthreads();
#pragma unroll
        for (int kk = 0; kk < 32; kk++) {
            float a0 = sa[ty * 4 + 0][kk], a1 = sa[ty * 4 + 1][kk];
            float a2 = sa[ty * 4 + 2][kk], a3 = sa[ty * 4 + 3][kk];
            float4 b4 = *reinterpret_cast<float4*>(&sb[kk][tx * 4]);
            acc[0][0] += a0 * b4.x; acc[0][1] += a0 * b4.y; acc[0][2] += a0 * b4.z; acc[0][3] += a0 * b4.w;
            acc[1][0] += a1 * b4.x; acc[1][1] += a1 * b4.y; acc[1][2] += a1 * b4.z; acc[1][3] += a1 * b4.w;
            acc[2][0] += a2 * b4.x; acc[2][1] += a2 * b4.y; acc[2][2] += a2 * b4.z; acc[2][3] += a2 * b4.w;
            acc[3][0] += a3 * b4.x; acc[3][1] += a3 * b4.y; acc[3][2] += a3 * b4.z; acc[3][3] += a3 * b4.w;
        }
        __syncthreads();
    }
#pragma unroll
    for (int i = 0; i < 4; i++) {
        int row = row0 + ty * 4 + i;
        float4 o;
        float* oc = reinterpret_cast<float*>(&o);
#pragma unroll
        for (int j = 0; j < 4; j++) {
            int col = col0 + tx * 4 + j;
            float v = acc[i][j] + b1[col];
            oc[j] = 0.5f * v * (1.0f + erff(v * 0.70710678118654752f));
        }
        *reinterpret_cast<float4*>(&H[(size_t)row * TWO_D + col0 + tx * 4]) = o;
    }
}

// ---------------- logits partials: fp32 GEMM, K split across blocks ----------
// grid (12 chunks, 32 token-blocks). chunks 0-7: H@W2 (K=1024), 8-11: x@Wg^T.
// partial[chunk][tok][m].  Staging pattern = proven round-3 gemm1 style.
__global__ __launch_bounds__(256) void k_logits(const float* __restrict__ H,
                                                const float* __restrict__ x,
                                                const float* __restrict__ W2,
                                                const float* __restrict__ Wg,
                                                float* __restrict__ partial) {
    __shared__ float sa[64][36];
    __shared__ float sb[32][64];
    int tx = threadIdx.x & 15, ty = threadIdx.x >> 4;
    int cx = blockIdx.x;
    int row0 = blockIdx.y * 64;

    const float* Asrc; int lda, koff;
    if (cx < 8) { Asrc = H; lda = TWO_D; koff = cx * 128; }
    else        { Asrc = x; lda = D_;    koff = (cx - 8) * 128; }

    float acc[4][4];
#pragma unroll
    for (int i = 0; i < 4; i++)
#pragma unroll
        for (int j = 0; j < 4; j++) acc[i][j] = 0.0f;

    for (int k0 = 0; k0 < 128; k0 += 32) {
#pragma unroll
        for (int q = 0; q < 2; q++) {
            int f = threadIdx.x * 2 + q;
            int r = f >> 3, c = (f & 7) * 4;
            *reinterpret_cast<float4*>(&sa[r][c]) =
                *reinterpret_cast<const float4*>(&Asrc[(size_t)(row0 + r) * lda + koff + k0 + c]);
            if (cx < 8) {
                int kk = f >> 4, n4 = (f & 15) * 4;
                *reinterpret_cast<float4*>(&sb[kk][n4]) =
                    *reinterpret_cast<const float4*>(&W2[(size_t)(koff + k0 + kk) * M_ + n4]);
            } else {
                int m = f >> 3, kq = f & 7;
                float4 v2 = *reinterpret_cast<const float4*>(&Wg[(size_t)m * D_ + koff + k0 + kq * 4]);
                sb[kq * 4 + 0][m] = v2.x; sb[kq * 4 + 1][m] = v2.y;
                sb[kq * 4 + 2][m] = v2.z; sb[kq * 4 + 3][m] = v2.w;
            }
        }
        __syncthreads();
#pragma unroll
        for (int kk = 0; kk < 32; kk++) {
            float a0 = sa[ty * 4 + 0][kk], a1 = sa[ty * 4 + 1][kk];
            float a2 = sa[ty * 4 + 2][kk], a3 = sa[ty * 4 + 3][kk];
            float4 b4 = *reinterpret_cast<float4*>(&sb[kk][tx * 4]);
            acc[0][0] += a0 * b4.x; acc[0][1] += a0 * b4.y; acc[0][2] += a0 * b4.z; acc[0][3] += a0 * b4.w;
            acc[1][0] += a1 * b4.x; acc[1][1] += a1 * b4.y; acc[1][2] += a1 * b4.z; acc[1][3] += a1 * b4.w;
            acc[2][0] += a2 * b4.x; acc[2][1] += a2 * b4.y; acc[2][2] += a2 * b4.z; acc[2][3] += a2 * b4.w;
            acc[3][0] += a3 * b4.x; acc[3][1] += a3 * b4.y; acc[3][2] += a3 * b4.z; acc[3][3] += a3 * b4.w;
        }
        __syncthreads();
    }
#pragma unroll
    for (int i = 0; i < 4; i++) {
        int row = row0 + ty * 4 + i;
        float4 o;
        float* oc = reinterpret_cast<float*>(&o);
#pragma unroll
        for (int j = 0; j < 4; j++) oc[j] = acc[i][j];
        *reinterpret_cast<float4*>(&partial[((size_t)cx * T_TOK + row) * M_ + tx * 4]) = o;
    }
}

// ---------------- top-k: reduce partials, softmax, top-4, bucket -------------
__global__ __launch_bounds__(256) void k_topk(const float* __restrict__ partial,
                                              const float* __restrict__ b2,
                                              const float* __restrict__ bg,
                                              int* __restrict__ counts,
                                              int* __restrict__ bslot,
                                              float* __restrict__ bw) {
    __shared__ float sglog[8][64];
    int t = threadIdx.x;
    int wave = t >> 6, lane = t & 63;
    int tok0 = blockIdx.x * 8;

    float l0, l1;
#pragma unroll
    for (int t2 = 0; t2 < 2; t2++) {
        int tok = tok0 + wave * 2 + t2;
        float acc = b2[lane];
#pragma unroll
        for (int c = 0; c < 8; c++)
            acc += partial[((size_t)c * T_TOK + tok) * M_ + lane];
        if (t2 == 0) l0 = acc; else l1 = acc;
        float ga = bg[lane];
#pragma unroll
        for (int c = 8; c < 12; c++)
            ga += partial[((size_t)c * T_TOK + tok) * M_ + lane];
        sglog[wave * 2 + t2][lane] = ga;
    }
    __syncthreads();

    for (int t2 = 0; t2 < 2; t2++) {
        int tt = wave * 2 + t2;
        int token = tok0 + tt;
        float l = (t2 == 0) ? l0 : l1;
        float mx = l;
#pragma unroll
        for (int off = 1; off < 64; off <<= 1) mx = fmaxf(mx, __shfl_xor(mx, off));
        float ev = expf(l - mx);
        float s = ev;
#pragma unroll
        for (int off = 1; off < 64; off <<= 1) s += __shfl_xor(s, off);
        float p = ev / s;

        float pm = p;
        int bi0, bi1, bi2, bi3; float bv0, bv1, bv2, bv3;
#pragma unroll
        for (int k = 0; k < 4; k++) {
            float bv = pm; int bi = lane;
#pragma unroll
            for (int off = 1; off < 64; off <<= 1) {
                float ov = __shfl_xor(bv, off);
                int   oi = __shfl_xor(bi, off);
                if (ov > bv || (ov == bv && oi < bi)) { bv = ov; bi = oi; }
            }
            if (k == 0) { bi0 = bi; bv0 = bv; }
            else if (k == 1) { bi1 = bi; bv1 = bv; }
            else if (k == 2) { bi2 = bi; bv2 = bv; }
            else { bi3 = bi; bv3 = bv; }
            if (lane == bi) pm = -1.0f;
        }
        float sum4 = bv0 + bv1 + bv2 + bv3;
        if (lane < 4) {
            int   e  = (lane == 0) ? bi0 : (lane == 1) ? bi1 : (lane == 2) ? bi2 : bi3;
            float pv = (lane == 0) ? bv0 : (lane == 1) ? bv1 : (lane == 2) ? bv2 : bv3;
            float g  = 1.0f / (1.0f + expf(-sglog[tt][e]));
            float w  = (pv / sum4) * g;
            int pos = atomicAdd(&counts[e], 1);
            bslot[e * T_TOK + pos] = token * 4 + lane;
            bw[e * T_TOK + pos]   = w;
        }
    }
}

// ---------------- grouped expert GEMM (bf16 MFMA) — round-3 proven version --
// per block: expert e, 64 bucket rows x 64 out cols, K=512
__global__ __launch_bounds__(256) void k_expert(const ushort* __restrict__ xs,
                                                const float* __restrict__ Wt,
                                                const float* __restrict__ bt,
                                                const float* __restrict__ ch,
                                                const int* __restrict__ counts,
                                                const int* __restrict__ bslot,
                                                const float* __restrict__ bw,
                                                float* __restrict__ scratch) {
    int e   = blockIdx.z;
    int cnt = counts[e];
    int y0  = blockIdx.y * 64;
    if (y0 >= cnt) return;
    int n0 = blockIdx.x * 64;

    __shared__ ushort sa[64][40];
    __shared__ ushort sbT[64][40];
    __shared__ int    s_slot[64];
    __shared__ float  s_w[64];

    int t = threadIdx.x;
    if (t < 64) {
        int i = y0 + t;
        if (i < cnt) { s_slot[t] = bslot[e * T_TOK + i]; s_w[t] = bw[e * T_TOK + i]; }
        else         { s_slot[t] = -1;                   s_w[t] = 0.0f; }
    }
    __syncthreads();

    int lane = t & 63, wave = t >> 6;
    int wm = wave >> 1, wn = wave & 1;
    int lr = lane & 15, kq = lane >> 4;

    f32x4 acc[2][2];
#pragma unroll
    for (int i = 0; i < 2; i++)
#pragma unroll
        for (int j = 0; j < 2; j++)
#pragma unroll
            for (int r = 0; r < 4; r++) acc[i][j][r] = 0.0f;

    for (int k0 = 0; k0 < D_; k0 += 32) {
        {
            int r = t >> 2, q = t & 3;
            int slot = s_slot[r];
            int tok = (slot >= 0) ? (slot >> 2) : 0;
            *reinterpret_cast<int4*>(&sa[r][q * 8]) =
                *reinterpret_cast<const int4*>(xs + (size_t)tok * TWO_D + k0 + q * 8);
        }
        {
#pragma unroll
            for (int q = 0; q < 2; q++) {
                int f = t * 2 + q;
                int k = f >> 4, n4 = (f & 15) * 4;
                float4 v = *reinterpret_cast<const float4*>(
                    &Wt[((size_t)e * D_ + (k0 + k)) * D_ + n0 + n4]);
                sbT[n4 + 0][k] = f2bf(v.x); sbT[n4 + 1][k] = f2bf(v.y);
                sbT[n4 + 2][k] = f2bf(v.z); sbT[n4 + 3][k] = f2bf(v.w);
            }
        }
        __syncthreads();
        bf16x8 af[2], bfr[2];
#pragma unroll
        for (int i = 0; i < 2; i++)
            af[i] = *reinterpret_cast<const bf16x8*>(&sa[wm * 32 + i * 16 + lr][kq * 8]);
#pragma unroll
        for (int j = 0; j < 2; j++)
            bfr[j] = *reinterpret_cast<const bf16x8*>(&sbT[wn * 32 + j * 16 + lr][kq * 8]);
#pragma unroll
        for (int i = 0; i < 2; i++)
#pragma unroll
            for (int j = 0; j < 2; j++)
                acc[i][j] = __builtin_amdgcn_mfma_f32_16x16x32_bf16(af[i], bfr[j], acc[i][j], 0, 0, 0);
        __syncthreads();
    }

#pragma unroll
    for (int i = 0; i < 2; i++)
#pragma unroll
        for (int j = 0; j < 2; j++) {
            int col = n0 + wn * 32 + j * 16 + lr;
            float bias = bt[(size_t)e * D_ + col] + ch[(size_t)e * D_ + col];
#pragma unroll
            for (int r = 0; r < 4; r++) {
                int rl = wm * 32 + i * 16 + kq * 4 + r;
                int slot = s_slot[rl];
                if (slot >= 0)
                    scratch[(size_t)slot * D_ + col] = (acc[i][j][r] + bias) * s_w[rl];
            }
        }
}

// ---------------- combine 4 slots -> selected (bf16) into xs[:, 512:] -------
__global__ __launch_bounds__(256) void k_combine(const float* __restrict__ scratch,
                                                 ushort* __restrict__ xs) {
    int tid = blockIdx.x * 256 + threadIdx.x;
    int token = tid >> 7;
    int d4 = (tid & 127) * 4;
    float4 a = *reinterpret_cast<const float4*>(scratch + ((size_t)token * 4 + 0) * D_ + d4);
    float4 b = *reinterpret_cast<const float4*>(scratch + ((size_t)token * 4 + 1) * D_ + d4);
    float4 c = *reinterpret_cast<const float4*>(scratch + ((size_t)token * 4 + 2) * D_ + d4);
    float4 d = *reinterpret_cast<const float4*>(scratch + ((size_t)token * 4 + 3) * D_ + d4);
    ushort4 o;
    o.x = f2bf(a.x + b.x + c.x + d.x);
    o.y = f2bf(a.y + b.y + c.y + d.y);
    o.z = f2bf(a.z + b.z + c.z + d.z);
    o.w = f2bf(a.w + b.w + c.w + d.w);
    *reinterpret_cast<ushort4*>(xs + (size_t)token * TWO_D + D_ + d4) = o;
}

// ---------------- integrate: out = [x, selected] @ int_W + int_b (bf16 MFMA)-
__global__ __launch_bounds__(256) void k_integrate(const ushort* __restrict__ xs,
                                                   const float* __restrict__ Wi,
                                                   const float* __restrict__ bi,
                                                   float* __restrict__ out) {
    int n0 = blockIdx.x * 64, r0 = blockIdx.y * 64;
    __shared__ ushort sa[64][40];
    __shared__ ushort sbT[64][40];
    int t = threadIdx.x, lane = t & 63, wave = t >> 6;
    int wm = wave >> 1, wn = wave & 1;
    int lr = lane & 15, kq = lane >> 4;

    f32x4 acc[2][2];
#pragma unroll
    for (int i = 0; i < 2; i++)
#pragma unroll
        for (int j = 0; j < 2; j++)
#pragma unroll
            for (int r = 0; r < 4; r++) acc[i][j][r] = 0.0f;

    for (int k0 = 0; k0 < TWO_D; k0 += 32) {
        {
            int r = t >> 2, q = t & 3;
            *reinterpret_cast<int4*>(&sa[r][q * 8]) =
                *reinterpret_cast<const int4*>(xs + (size_t)(r0 + r) * TWO_D + k0 + q * 8);
        }
        {
#pragma unroll
            for (int q = 0; q < 2; q++) {
                int f = t * 2 + q;
                int k = f >> 4, n4 = (f & 15) * 4;
                float4 v = *reinterpret_cast<const float4*>(&Wi[(size_t)(k0 + k) * D_ + n0 + n4]);
                sbT[n4 + 0][k] = f2bf(v.x); sbT[n4 + 1][k] = f2bf(v.y);
                sbT[n4 + 2][k] = f2bf(v.z); sbT[n4 + 3][k] = f2bf(v.w);
            }
        }
        __syncthreads();
        bf16x8 af[2], bfr[2];
#pragma unroll
        for (int i = 0; i < 2; i++)
            af[i] = *reinterpret_cast<const bf16x8*>(&sa[wm * 32 + i * 16 + lr][kq * 8]);
#pragma unroll
        for (int j = 0; j < 2; j++)
            bfr[j] = *reinterpret_cast<const bf16x8*>(&sbT[wn * 32 + j * 16 + lr][kq * 8]);
#pragma unroll
        for (int i = 0; i < 2; i++)
#pragma unroll
            for (int j = 0; j < 2; j++)
                acc[i][j] = __builtin_amdgcn_mfma_f32_16x16x32_bf16(af[i], bfr[j], acc[i][j], 0, 0, 0);
        __syncthreads();
    }

#pragma unroll
    for (int i = 0; i < 2; i++)
#pragma unroll
        for (int j = 0; j < 2; j++) {
            int col = n0 + wn * 32 + j * 16 + lr;
            float bb = bi[col];
#pragma unroll
            for (int r = 0; r < 4; r++) {
                int row = r0 + wm * 32 + i * 16 + kq * 4 + r;
                out[(size_t)row * D_ + col] = acc[i][j][r] + bb;
            }
        }
}

extern "C" void kernel_launch(void* const* d_in, const int* in_sizes, int n_in,
                              void* d_out, int out_size, void* d_ws, size_t ws_size,
                              hipStream_t stream) {
    const float* x   = (const float*)d_in[0];
    const float* ctx = (const float*)d_in[1];
    const float* Wt  = (const float*)d_in[2];
    const float* bt  = (const float*)d_in[3];
    const float* ch  = (const float*)d_in[4];
    const float* Wg  = (const float*)d_in[5];
    const float* bg  = (const float*)d_in[6];
    const float* W1  = (const float*)d_in[7];
    const float* b1  = (const float*)d_in[8];
    const float* W2  = (const float*)d_in[9];
    const float* b2  = (const float*)d_in[10];
    const float* Wi  = (const float*)d_in[11];
    const float* bi  = (const float*)d_in[12];
    float* out = (float*)d_out;

    char* ws = (char*)d_ws;
    float*  H       = (float*)(ws + 0);                 //  8 MB
    ushort* xs      = (ushort*)(ws + 8388608);          //  4 MB
    int*    counts  = (int*)(ws + 12582912);            //  1 KB
    int*    bslot   = (int*)(ws + 12583936);            // 512 KB
    float*  bw      = (float*)(ws + 13108224);          // 512 KB
    float*  scratch = (float*)(ws + 13632512);          // 16 MB
    float*  partial = scratch;                          //  6 MB alias (dead before expert)

    hipMemsetAsync(counts, 0, 256, stream);
    k_cast_x  <<<1024, 256, 0, stream>>>(x, xs);
    k_gemm1   <<<dim3(16, 32), 256, 0, stream>>>(ctx, W1, b1, H);
    k_logits  <<<dim3(12, 32), 256, 0, stream>>>(H, x, W2, Wg, partial);
    k_topk    <<<256, 256, 0, stream>>>(partial, b2, bg, counts, bslot, bw);
    k_expert  <<<dim3(8, 32, 64), 256, 0, stream>>>(xs, Wt, bt, ch, counts, bslot, bw, scratch);
    k_combine <<<1024, 256, 0, stream>>>(scratch, xs);
    k_integrate<<<dim3(8, 32), 256, 0, stream>>>(xs, Wi, bi, out);
}

// Round 7
// 167.703 us; speedup vs baseline: 1.1816x; 1.0665x over previous
//
#include <hip/hip_runtime.h>
#include <hip/hip_bf16.h>

#define T_TOK 2048
#define D_    512
#define TWO_D 1024
#define M_    64

typedef float  f32x4  __attribute__((ext_vector_type(4)));
typedef __bf16 bf16x8 __attribute__((ext_vector_type(8)));

__device__ __forceinline__ ushort f2bf(float f) {
    union { __hip_bfloat16 h; ushort u; } cv;
    cv.h = __float2bfloat16(f);
    return cv.u;
}

// ---------------- cast x (f32) -> xs[:, 0:512] (bf16), xs is [2048][1024] ----
__global__ __launch_bounds__(256) void k_cast_x(const float* __restrict__ x,
                                                ushort* __restrict__ xs) {
    int idx = blockIdx.x * 256 + threadIdx.x;
    int e4  = idx * 4;
    int t   = e4 >> 9;
    int d   = e4 & 511;
    float4 v = *reinterpret_cast<const float4*>(x + e4);
    ushort4 o;
    o.x = f2bf(v.x); o.y = f2bf(v.y); o.z = f2bf(v.z); o.w = f2bf(v.w);
    *reinterpret_cast<ushort4*>(xs + (size_t)t * TWO_D + d) = o;
}

// ---------------- selector GEMM1: H = gelu(context @ sel_W1 + b1), fp32 ------
// Register-prefetch double-buffered staging (next K-tile in flight under FMA).
__global__ __launch_bounds__(256) void k_gemm1(const float* __restrict__ A,
                                               const float* __restrict__ W1,
                                               const float* __restrict__ b1,
                                               float* __restrict__ H) {
    __shared__ float sa[64][36];
    __shared__ float sb[32][64];
    int tx = threadIdx.x & 15, ty = threadIdx.x >> 4;
    int col0 = blockIdx.x * 64, row0 = blockIdx.y * 64;

    // load roles (two A float4s, two B float4s per thread)
    int f0 = threadIdx.x * 2, f1 = f0 + 1;
    int ra0 = f0 >> 3, ca0 = (f0 & 7) * 4;
    int ra1 = f1 >> 3, ca1 = (f1 & 7) * 4;
    int kb0 = f0 >> 4, nb0 = (f0 & 15) * 4;
    int kb1 = f1 >> 4, nb1 = (f1 & 15) * 4;
    const float* pa0 = &A[(size_t)(row0 + ra0) * D_ + ca0];
    const float* pa1 = &A[(size_t)(row0 + ra1) * D_ + ca1];
    const float* pb0 = &W1[(size_t)kb0 * TWO_D + col0 + nb0];
    const float* pb1 = &W1[(size_t)kb1 * TWO_D + col0 + nb1];

    float acc[4][4];
#pragma unroll
    for (int i = 0; i < 4; i++)
#pragma unroll
        for (int j = 0; j < 4; j++) acc[i][j] = 0.0f;

    float4 a0c = *reinterpret_cast<const float4*>(pa0);
    float4 a1c = *reinterpret_cast<const float4*>(pa1);
    float4 b0c = *reinterpret_cast<const float4*>(pb0);
    float4 b1c = *reinterpret_cast<const float4*>(pb1);

    for (int k0 = 0; k0 < D_; k0 += 32) {
        float4 a0n = a0c, a1n = a1c, b0n = b0c, b1n = b1c;
        if (k0 + 32 < D_) {
            a0n = *reinterpret_cast<const float4*>(pa0 + k0 + 32);
            a1n = *reinterpret_cast<const float4*>(pa1 + k0 + 32);
            b0n = *reinterpret_cast<const float4*>(pb0 + (size_t)(k0 + 32) * TWO_D);
            b1n = *reinterpret_cast<const float4*>(pb1 + (size_t)(k0 + 32) * TWO_D);
        }
        *reinterpret_cast<float4*>(&sa[ra0][ca0]) = a0c;
        *reinterpret_cast<float4*>(&sa[ra1][ca1]) = a1c;
        *reinterpret_cast<float4*>(&sb[kb0][nb0]) = b0c;
        *reinterpret_cast<float4*>(&sb[kb1][nb1]) = b1c;
        __syncthreads();
#pragma unroll
        for (int kk = 0; kk < 32; kk++) {
            float v0 = sa[ty * 4 + 0][kk], v1 = sa[ty * 4 + 1][kk];
            float v2 = sa[ty * 4 + 2][kk], v3 = sa[ty * 4 + 3][kk];
            float4 b4 = *reinterpret_cast<float4*>(&sb[kk][tx * 4]);
            acc[0][0] += v0 * b4.x; acc[0][1] += v0 * b4.y; acc[0][2] += v0 * b4.z; acc[0][3] += v0 * b4.w;
            acc[1][0] += v1 * b4.x; acc[1][1] += v1 * b4.y; acc[1][2] += v1 * b4.z; acc[1][3] += v1 * b4.w;
            acc[2][0] += v2 * b4.x; acc[2][1] += v2 * b4.y; acc[2][2] += v2 * b4.z; acc[2][3] += v2 * b4.w;
            acc[3][0] += v3 * b4.x; acc[3][1] += v3 * b4.y; acc[3][2] += v3 * b4.z; acc[3][3] += v3 * b4.w;
        }
        __syncthreads();
        a0c = a0n; a1c = a1n; b0c = b0n; b1c = b1n;
    }
#pragma unroll
    for (int i = 0; i < 4; i++) {
        int row = row0 + ty * 4 + i;
        float4 o;
        float* oc = reinterpret_cast<float*>(&o);
#pragma unroll
        for (int j = 0; j < 4; j++) {
            int col = col0 + tx * 4 + j;
            float v = acc[i][j] + b1[col];
            oc[j] = 0.5f * v * (1.0f + erff(v * 0.70710678118654752f));
        }
        *reinterpret_cast<float4*>(&H[(size_t)row * TWO_D + col0 + tx * 4]) = o;
    }
}

// ---------------- logits partials: fp32 GEMM, K split across blocks ----------
__global__ __launch_bounds__(256) void k_logits(const float* __restrict__ H,
                                                const float* __restrict__ x,
                                                const float* __restrict__ W2,
                                                const float* __restrict__ Wg,
                                                float* __restrict__ partial) {
    __shared__ float sa[64][36];
    __shared__ float sb[32][64];
    int tx = threadIdx.x & 15, ty = threadIdx.x >> 4;
    int cx = blockIdx.x;
    int row0 = blockIdx.y * 64;

    const float* Asrc; int lda, koff;
    if (cx < 8) { Asrc = H; lda = TWO_D; koff = cx * 128; }
    else        { Asrc = x; lda = D_;    koff = (cx - 8) * 128; }

    float acc[4][4];
#pragma unroll
    for (int i = 0; i < 4; i++)
#pragma unroll
        for (int j = 0; j < 4; j++) acc[i][j] = 0.0f;

    for (int k0 = 0; k0 < 128; k0 += 32) {
#pragma unroll
        for (int q = 0; q < 2; q++) {
            int f = threadIdx.x * 2 + q;
            int r = f >> 3, c = (f & 7) * 4;
            *reinterpret_cast<float4*>(&sa[r][c]) =
                *reinterpret_cast<const float4*>(&Asrc[(size_t)(row0 + r) * lda + koff + k0 + c]);
            if (cx < 8) {
                int kk = f >> 4, n4 = (f & 15) * 4;
                *reinterpret_cast<float4*>(&sb[kk][n4]) =
                    *reinterpret_cast<const float4*>(&W2[(size_t)(koff + k0 + kk) * M_ + n4]);
            } else {
                int m = f >> 3, kq = f & 7;
                float4 v2 = *reinterpret_cast<const float4*>(&Wg[(size_t)m * D_ + koff + k0 + kq * 4]);
                sb[kq * 4 + 0][m] = v2.x; sb[kq * 4 + 1][m] = v2.y;
                sb[kq * 4 + 2][m] = v2.z; sb[kq * 4 + 3][m] = v2.w;
            }
        }
        __syncthreads();
#pragma unroll
        for (int kk = 0; kk < 32; kk++) {
            float a0 = sa[ty * 4 + 0][kk], a1 = sa[ty * 4 + 1][kk];
            float a2 = sa[ty * 4 + 2][kk], a3 = sa[ty * 4 + 3][kk];
            float4 b4 = *reinterpret_cast<float4*>(&sb[kk][tx * 4]);
            acc[0][0] += a0 * b4.x; acc[0][1] += a0 * b4.y; acc[0][2] += a0 * b4.z; acc[0][3] += a0 * b4.w;
            acc[1][0] += a1 * b4.x; acc[1][1] += a1 * b4.y; acc[1][2] += a1 * b4.z; acc[1][3] += a1 * b4.w;
            acc[2][0] += a2 * b4.x; acc[2][1] += a2 * b4.y; acc[2][2] += a2 * b4.z; acc[2][3] += a2 * b4.w;
            acc[3][0] += a3 * b4.x; acc[3][1] += a3 * b4.y; acc[3][2] += a3 * b4.z; acc[3][3] += a3 * b4.w;
        }
        __syncthreads();
    }
#pragma unroll
    for (int i = 0; i < 4; i++) {
        int row = row0 + ty * 4 + i;
        float4 o;
        float* oc = reinterpret_cast<float*>(&o);
#pragma unroll
        for (int j = 0; j < 4; j++) oc[j] = acc[i][j];
        *reinterpret_cast<float4*>(&partial[((size_t)cx * T_TOK + row) * M_ + tx * 4]) = o;
    }
}

// ---------------- top-k: reduce partials, softmax, top-4, bucket -------------
__global__ __launch_bounds__(256) void k_topk(const float* __restrict__ partial,
                                              const float* __restrict__ b2,
                                              const float* __restrict__ bg,
                                              int* __restrict__ counts,
                                              int* __restrict__ bslot,
                                              float* __restrict__ bw) {
    __shared__ float sglog[8][64];
    int t = threadIdx.x;
    int wave = t >> 6, lane = t & 63;
    int tok0 = blockIdx.x * 8;

    float l0, l1;
#pragma unroll
    for (int t2 = 0; t2 < 2; t2++) {
        int tok = tok0 + wave * 2 + t2;
        float acc = b2[lane];
#pragma unroll
        for (int c = 0; c < 8; c++)
            acc += partial[((size_t)c * T_TOK + tok) * M_ + lane];
        if (t2 == 0) l0 = acc; else l1 = acc;
        float ga = bg[lane];
#pragma unroll
        for (int c = 8; c < 12; c++)
            ga += partial[((size_t)c * T_TOK + tok) * M_ + lane];
        sglog[wave * 2 + t2][lane] = ga;
    }
    __syncthreads();

    for (int t2 = 0; t2 < 2; t2++) {
        int tt = wave * 2 + t2;
        int token = tok0 + tt;
        float l = (t2 == 0) ? l0 : l1;
        float mx = l;
#pragma unroll
        for (int off = 1; off < 64; off <<= 1) mx = fmaxf(mx, __shfl_xor(mx, off));
        float ev = expf(l - mx);
        float s = ev;
#pragma unroll
        for (int off = 1; off < 64; off <<= 1) s += __shfl_xor(s, off);
        float p = ev / s;

        float pm = p;
        int bi0, bi1, bi2, bi3; float bv0, bv1, bv2, bv3;
#pragma unroll
        for (int k = 0; k < 4; k++) {
            float bv = pm; int bi = lane;
#pragma unroll
            for (int off = 1; off < 64; off <<= 1) {
                float ov = __shfl_xor(bv, off);
                int   oi = __shfl_xor(bi, off);
                if (ov > bv || (ov == bv && oi < bi)) { bv = ov; bi = oi; }
            }
            if (k == 0) { bi0 = bi; bv0 = bv; }
            else if (k == 1) { bi1 = bi; bv1 = bv; }
            else if (k == 2) { bi2 = bi; bv2 = bv; }
            else { bi3 = bi; bv3 = bv; }
            if (lane == bi) pm = -1.0f;
        }
        float sum4 = bv0 + bv1 + bv2 + bv3;
        if (lane < 4) {
            int   e  = (lane == 0) ? bi0 : (lane == 1) ? bi1 : (lane == 2) ? bi2 : bi3;
            float pv = (lane == 0) ? bv0 : (lane == 1) ? bv1 : (lane == 2) ? bv2 : bv3;
            float g  = 1.0f / (1.0f + expf(-sglog[tt][e]));
            float w  = (pv / sum4) * g;
            int pos = atomicAdd(&counts[e], 1);
            bslot[e * T_TOK + pos] = token * 4 + lane;
            bw[e * T_TOK + pos]   = w;
        }
    }
}

// ---------------- grouped expert GEMM (bf16 MFMA), register-prefetch --------
// per block: expert e, 64 bucket rows x 64 out cols, K=512
__global__ __launch_bounds__(256) void k_expert(const ushort* __restrict__ xs,
                                                const float* __restrict__ Wt,
                                                const float* __restrict__ bt,
                                                const float* __restrict__ ch,
                                                const int* __restrict__ counts,
                                                const int* __restrict__ bslot,
                                                const float* __restrict__ bw,
                                                float* __restrict__ scratch) {
    int e   = blockIdx.z;
    int cnt = counts[e];
    int y0  = blockIdx.y * 64;
    if (y0 >= cnt) return;
    int n0 = blockIdx.x * 64;

    __shared__ ushort sa[64][40];
    __shared__ ushort sbT[64][40];
    __shared__ int    s_slot[64];
    __shared__ float  s_w[64];

    int t = threadIdx.x;
    if (t < 64) {
        int i = y0 + t;
        if (i < cnt) { s_slot[t] = bslot[e * T_TOK + i]; s_w[t] = bw[e * T_TOK + i]; }
        else         { s_slot[t] = -1;                   s_w[t] = 0.0f; }
    }
    __syncthreads();

    int lane = t & 63, wave = t >> 6;
    int wm = wave >> 1, wn = wave & 1;
    int lr = lane & 15, kq = lane >> 4;

    // staging roles
    int r_a = t >> 2, q_a = t & 3;
    int slot_a = s_slot[r_a];
    const ushort* pa = xs + (size_t)((slot_a >= 0) ? (slot_a >> 2) : 0) * TWO_D + q_a * 8;
    int f0 = t * 2, f1 = f0 + 1;
    int kb0 = f0 >> 4, nb0 = (f0 & 15) * 4;
    int kb1 = f1 >> 4, nb1 = (f1 & 15) * 4;
    const float* pb0 = &Wt[((size_t)e * D_ + kb0) * D_ + n0 + nb0];
    const float* pb1 = &Wt[((size_t)e * D_ + kb1) * D_ + n0 + nb1];

    f32x4 acc[2][2];
#pragma unroll
    for (int i = 0; i < 2; i++)
#pragma unroll
        for (int j = 0; j < 2; j++)
#pragma unroll
            for (int r = 0; r < 4; r++) acc[i][j][r] = 0.0f;

    int4  a_c  = *reinterpret_cast<const int4*>(pa);
    float4 b0c = *reinterpret_cast<const float4*>(pb0);
    float4 b1c = *reinterpret_cast<const float4*>(pb1);

    for (int k0 = 0; k0 < D_; k0 += 32) {
        int4 a_n = a_c; float4 b0n = b0c, b1n = b1c;
        if (k0 + 32 < D_) {
            a_n = *reinterpret_cast<const int4*>(pa + k0 + 32);
            b0n = *reinterpret_cast<const float4*>(pb0 + (size_t)(k0 + 32) * D_);
            b1n = *reinterpret_cast<const float4*>(pb1 + (size_t)(k0 + 32) * D_);
        }
        *reinterpret_cast<int4*>(&sa[r_a][q_a * 8]) = a_c;
        sbT[nb0 + 0][kb0] = f2bf(b0c.x); sbT[nb0 + 1][kb0] = f2bf(b0c.y);
        sbT[nb0 + 2][kb0] = f2bf(b0c.z); sbT[nb0 + 3][kb0] = f2bf(b0c.w);
        sbT[nb1 + 0][kb1] = f2bf(b1c.x); sbT[nb1 + 1][kb1] = f2bf(b1c.y);
        sbT[nb1 + 2][kb1] = f2bf(b1c.z); sbT[nb1 + 3][kb1] = f2bf(b1c.w);
        __syncthreads();
        bf16x8 af[2], bfr[2];
#pragma unroll
        for (int i = 0; i < 2; i++)
            af[i] = *reinterpret_cast<const bf16x8*>(&sa[wm * 32 + i * 16 + lr][kq * 8]);
#pragma unroll
        for (int j = 0; j < 2; j++)
            bfr[j] = *reinterpret_cast<const bf16x8*>(&sbT[wn * 32 + j * 16 + lr][kq * 8]);
#pragma unroll
        for (int i = 0; i < 2; i++)
#pragma unroll
            for (int j = 0; j < 2; j++)
                acc[i][j] = __builtin_amdgcn_mfma_f32_16x16x32_bf16(af[i], bfr[j], acc[i][j], 0, 0, 0);
        __syncthreads();
        a_c = a_n; b0c = b0n; b1c = b1n;
    }

#pragma unroll
    for (int i = 0; i < 2; i++)
#pragma unroll
        for (int j = 0; j < 2; j++) {
            int col = n0 + wn * 32 + j * 16 + lr;
            float bias = bt[(size_t)e * D_ + col] + ch[(size_t)e * D_ + col];
#pragma unroll
            for (int r = 0; r < 4; r++) {
                int rl = wm * 32 + i * 16 + kq * 4 + r;
                int slot = s_slot[rl];
                if (slot >= 0)
                    scratch[(size_t)slot * D_ + col] = (acc[i][j][r] + bias) * s_w[rl];
            }
        }
}

// ---------------- combine 4 slots -> selected (bf16) into xs[:, 512:] -------
__global__ __launch_bounds__(256) void k_combine(const float* __restrict__ scratch,
                                                 ushort* __restrict__ xs) {
    int tid = blockIdx.x * 256 + threadIdx.x;
    int token = tid >> 7;
    int d4 = (tid & 127) * 4;
    float4 a = *reinterpret_cast<const float4*>(scratch + ((size_t)token * 4 + 0) * D_ + d4);
    float4 b = *reinterpret_cast<const float4*>(scratch + ((size_t)token * 4 + 1) * D_ + d4);
    float4 c = *reinterpret_cast<const float4*>(scratch + ((size_t)token * 4 + 2) * D_ + d4);
    float4 d = *reinterpret_cast<const float4*>(scratch + ((size_t)token * 4 + 3) * D_ + d4);
    ushort4 o;
    o.x = f2bf(a.x + b.x + c.x + d.x);
    o.y = f2bf(a.y + b.y + c.y + d.y);
    o.z = f2bf(a.z + b.z + c.z + d.z);
    o.w = f2bf(a.w + b.w + c.w + d.w);
    *reinterpret_cast<ushort4*>(xs + (size_t)token * TWO_D + D_ + d4) = o;
}

// ---------------- integrate: out = [x, selected] @ int_W + int_b ------------
__global__ __launch_bounds__(256) void k_integrate(const ushort* __restrict__ xs,
                                                   const float* __restrict__ Wi,
                                                   const float* __restrict__ bi,
                                                   float* __restrict__ out) {
    int n0 = blockIdx.x * 64, r0 = blockIdx.y * 64;
    __shared__ ushort sa[64][40];
    __shared__ ushort sbT[64][40];
    int t = threadIdx.x, lane = t & 63, wave = t >> 6;
    int wm = wave >> 1, wn = wave & 1;
    int lr = lane & 15, kq = lane >> 4;

    // staging roles
    int r_a = t >> 2, q_a = t & 3;
    const ushort* pa = xs + (size_t)(r0 + r_a) * TWO_D + q_a * 8;
    int f0 = t * 2, f1 = f0 + 1;
    int kb0 = f0 >> 4, nb0 = (f0 & 15) * 4;
    int kb1 = f1 >> 4, nb1 = (f1 & 15) * 4;
    const float* pb0 = &Wi[(size_t)kb0 * D_ + n0 + nb0];
    const float* pb1 = &Wi[(size_t)kb1 * D_ + n0 + nb1];

    f32x4 acc[2][2];
#pragma unroll
    for (int i = 0; i < 2; i++)
#pragma unroll
        for (int j = 0; j < 2; j++)
#pragma unroll
            for (int r = 0; r < 4; r++) acc[i][j][r] = 0.0f;

    int4  a_c  = *reinterpret_cast<const int4*>(pa);
    float4 b0c = *reinterpret_cast<const float4*>(pb0);
    float4 b1c = *reinterpret_cast<const float4*>(pb1);

    for (int k0 = 0; k0 < TWO_D; k0 += 32) {
        int4 a_n = a_c; float4 b0n = b0c, b1n = b1c;
        if (k0 + 32 < TWO_D) {
            a_n = *reinterpret_cast<const int4*>(pa + k0 + 32);
            b0n = *reinterpret_cast<const float4*>(pb0 + (size_t)(k0 + 32) * D_);
            b1n = *reinterpret_cast<const float4*>(pb1 + (size_t)(k0 + 32) * D_);
        }
        *reinterpret_cast<int4*>(&sa[r_a][q_a * 8]) = a_c;
        sbT[nb0 + 0][kb0] = f2bf(b0c.x); sbT[nb0 + 1][kb0] = f2bf(b0c.y);
        sbT[nb0 + 2][kb0] = f2bf(b0c.z); sbT[nb0 + 3][kb0] = f2bf(b0c.w);
        sbT[nb1 + 0][kb1] = f2bf(b1c.x); sbT[nb1 + 1][kb1] = f2bf(b1c.y);
        sbT[nb1 + 2][kb1] = f2bf(b1c.z); sbT[nb1 + 3][kb1] = f2bf(b1c.w);
        __syncthreads();
        bf16x8 af[2], bfr[2];
#pragma unroll
        for (int i = 0; i < 2; i++)
            af[i] = *reinterpret_cast<const bf16x8*>(&sa[wm * 32 + i * 16 + lr][kq * 8]);
#pragma unroll
        for (int j = 0; j < 2; j++)
            bfr[j] = *reinterpret_cast<const bf16x8*>(&sbT[wn * 32 + j * 16 + lr][kq * 8]);
#pragma unroll
        for (int i = 0; i < 2; i++)
#pragma unroll
            for (int j = 0; j < 2; j++)
                acc[i][j] = __builtin_amdgcn_mfma_f32_16x16x32_bf16(af[i], bfr[j], acc[i][j], 0, 0, 0);
        __syncthreads();
        a_c = a_n; b0c = b0n; b1c = b1n;
    }

#pragma unroll
    for (int i = 0; i < 2; i++)
#pragma unroll
        for (int j = 0; j < 2; j++) {
            int col = n0 + wn * 32 + j * 16 + lr;
            float bb = bi[col];
#pragma unroll
            for (int r = 0; r < 4; r++) {
                int row = r0 + wm * 32 + i * 16 + kq * 4 + r;
                out[(size_t)row * D_ + col] = acc[i][j][r] + bb;
            }
        }
}

extern "C" void kernel_launch(void* const* d_in, const int* in_sizes, int n_in,
                              void* d_out, int out_size, void* d_ws, size_t ws_size,
                              hipStream_t stream) {
    const float* x   = (const float*)d_in[0];
    const float* ctx = (const float*)d_in[1];
    const float* Wt  = (const float*)d_in[2];
    const float* bt  = (const float*)d_in[3];
    const float* ch  = (const float*)d_in[4];
    const float* Wg  = (const float*)d_in[5];
    const float* bg  = (const float*)d_in[6];
    const float* W1  = (const float*)d_in[7];
    const float* b1  = (const float*)d_in[8];
    const float* W2  = (const float*)d_in[9];
    const float* b2  = (const float*)d_in[10];
    const float* Wi  = (const float*)d_in[11];
    const float* bi  = (const float*)d_in[12];
    float* out = (float*)d_out;

    char* ws = (char*)d_ws;
    float*  H       = (float*)(ws + 0);                 //  8 MB
    ushort* xs      = (ushort*)(ws + 8388608);          //  4 MB
    int*    counts  = (int*)(ws + 12582912);            //  1 KB
    int*    bslot   = (int*)(ws + 12583936);            // 512 KB
    float*  bw      = (float*)(ws + 13108224);          // 512 KB
    float*  scratch = (float*)(ws + 13632512);          // 16 MB
    float*  partial = scratch;                          //  6 MB alias (dead before expert)

    hipMemsetAsync(counts, 0, 256, stream);
    k_cast_x  <<<1024, 256, 0, stream>>>(x, xs);
    k_gemm1   <<<dim3(16, 32), 256, 0, stream>>>(ctx, W1, b1, H);
    k_logits  <<<dim3(12, 32), 256, 0, stream>>>(H, x, W2, Wg, partial);
    k_topk    <<<256, 256, 0, stream>>>(partial, b2, bg, counts, bslot, bw);
    k_expert  <<<dim3(8, 32, 64), 256, 0, stream>>>(xs, Wt, bt, ch, counts, bslot, bw, scratch);
    k_combine <<<1024, 256, 0, stream>>>(scratch, xs);
    k_integrate<<<dim3(8, 32), 256, 0, stream>>>(xs, Wi, bi, out);
}